// Round 10
// baseline (89.075 us; speedup 1.0000x reference)
//
#include <hip/hip_runtime.h>
#include <hip/hip_bf16.h>

typedef __attribute__((ext_vector_type(4)))  short short4v;
typedef __attribute__((ext_vector_type(8)))  short short8;
typedef __attribute__((ext_vector_type(16))) float float16v;

#define T_LEN 4096
#define L_LEN 128
#define NWIN  3969
#define CK    128
#define XSTR  4100   // xb row stride (elems): +4 pad -> b64 reads <=3-way banked

__device__ __forceinline__ unsigned short f2bf(float f) {
    unsigned u = __float_as_uint(f);
    u += 0x7fffu + ((u >> 16) & 1u);          // RNE
    return (unsigned short)(u >> 16);
}

// 128 blocks x 128 threads: normalize shapelet ck=blockIdx, natural layout
__global__ void prep_sh(const float* __restrict__ sh,
                        unsigned short* __restrict__ wsB) {
    const int ck = blockIdx.x;       // 0..127
    const int l  = threadIdx.x;      // 0..127
    __shared__ float rs[2], rq[2];
    const int lane = l & 63, wv = l >> 6;

    float v = sh[ck * L_LEN + l];
    float s = v, q = v * v;
    #pragma unroll
    for (int off = 32; off >= 1; off >>= 1) {
        s += __shfl_xor(s, off);
        q += __shfl_xor(q, off);
    }
    if (lane == 0) { rs[wv] = s; rq[wv] = q; }
    __syncthreads();
    float sm = rs[0] + rs[1], sq = rq[0] + rq[1];
    float mu  = sm * (1.f / L_LEN);
    float var = fmaxf(sq * (1.f / L_LEN) - mu * mu, 0.f);
    float inv = 1.f / (sqrtf(var) + 1e-6f);
    wsB[ck * L_LEN + l] = f2bf((v - mu) * inv);   // natural [ck][128] bf16
}

// one block per row; 512 threads = 8 waves = 2 waves/SIMD (256-reg budget).
// wave (mt = wv&3, nh = wv>>2): windows [T0+32mt, T0+32mt+32), shapelets
// ck in [64nh, 64nh+64) as two 32-wide n-tiles. 32x32x16 MFMA:
//   A: m=lane&31, k=8*(lane>>5)+j   B: n=lane&31, k=8*(lane>>5)+j
//   C/D: col=lane&31, row=(reg&3)+8*(reg>>2)+4*(lane>>5)
__global__ __launch_bounds__(512, 2)
void conv_row(const float* __restrict__ x,
              const unsigned short* __restrict__ wsB,
              float* __restrict__ out) {
    __shared__ alignas(16) unsigned short xb[8 * XSTR]; // 65.6 KB shifted copies
    __shared__ float sty[T_LEN];                        // 16 KB: 1/(sd*L)
    __shared__ float PSs[513], PQs[513];
    __shared__ float grpS[8], grpQ[8];
    __shared__ float wmax[8][2][32];                    // 2 KB

    const int tid  = threadIdx.x;
    const int lane = tid & 63;
    const int wv   = tid >> 6;
    const int row  = blockIdx.x;
    const float4* xr4 = (const float4*)(x + row * T_LEN);

    const int mt = wv & 3, nh = wv >> 2;
    const int m32 = lane & 31, h = lane >> 5;

    // ---- B fragments -> 64 registers per wave (once per row) ----
    short8 Bf[2][8];
    #pragma unroll
    for (int nt2 = 0; nt2 < 2; ++nt2) {
        const int ck = 32 * (2 * nh + nt2) + m32;
        #pragma unroll
        for (int ks = 0; ks < 8; ++ks)
            Bf[nt2][ks] = *(const short8*)&wsB[ck * L_LEN + 16 * ks + 8 * h];
    }

    // ---- stage row: thread t owns elems [8t,8t+8), loads 16 (overlap) ----
    float v[16];
    {
        float4 a0 = xr4[2 * tid];
        float4 a1 = xr4[2 * tid + 1];
        float4 a2 = make_float4(0.f, 0.f, 0.f, 0.f), a3 = a2;
        if (tid < 511) { a2 = xr4[2 * tid + 2]; a3 = xr4[2 * tid + 3]; }
        v[0]=a0.x; v[1]=a0.y; v[2]=a0.z;  v[3]=a0.w;
        v[4]=a1.x; v[5]=a1.y; v[6]=a1.z;  v[7]=a1.w;
        v[8]=a2.x; v[9]=a2.y; v[10]=a2.z; v[11]=a2.w;
        v[12]=a3.x; v[13]=a3.y; v[14]=a3.z; v[15]=a3.w;
    }
    unsigned short bb[16];
    #pragma unroll
    for (int i = 0; i < 16; ++i) bb[i] = f2bf(v[i]);
    #pragma unroll
    for (int c = 0; c < 8; ++c) {           // copy_c[i] = x[i+c]; b64 pairs
        short4v lo, hi;
        #pragma unroll
        for (int j = 0; j < 4; ++j) { lo[j] = (short)bb[c + j]; hi[j] = (short)bb[c + 4 + j]; }
        *(short4v*)&xb[c * XSTR + 8 * tid]     = lo;
        *(short4v*)&xb[c * XSTR + 8 * tid + 4] = hi;
    }

    // ---- seg sums + block scan -> elem-granular prefix @8 ----
    float s = 0.f, q = 0.f;
    #pragma unroll
    for (int i = 0; i < 8; ++i) { s += v[i]; q += v[i] * v[i]; }
    float is = s, iq = q;
    #pragma unroll
    for (int off = 1; off < 64; off <<= 1) {
        float ts = __shfl_up(is, off);
        float tq = __shfl_up(iq, off);
        if (lane >= off) { is += ts; iq += tq; }
    }
    if (lane == 63) { grpS[wv] = is; grpQ[wv] = iq; }
    __syncthreads();
    float os = 0.f, oq = 0.f;
    #pragma unroll
    for (int w = 0; w < 7; ++w) if (w < wv) { os += grpS[w]; oq += grpQ[w]; }
    PSs[tid] = os + is - s;                 // exclusive prefix at elem 8*tid
    PQs[tid] = oq + iq - q;
    if (tid == 511) { PSs[512] = os + is; PQs[512] = oq + iq; }
    __syncthreads();

    // ---- window stats: thread t -> windows [8t, 8t+8), incremental ----
    if (tid < 497) {
        float S = PSs[tid + 16] - PSs[tid];
        float Q = PQs[tid + 16] - PQs[tid];
        float4 b0 = make_float4(0.f, 0.f, 0.f, 0.f), b1 = b0;
        if (tid <= 495) { b0 = xr4[2 * tid + 32]; b1 = xr4[2 * tid + 33]; }
        float xn[8] = {b0.x, b0.y, b0.z, b0.w, b1.x, b1.y, b1.z, b1.w};
        #pragma unroll
        for (int e = 0; e < 8; ++e) {
            int w = 8 * tid + e;
            if (w < NWIN) {
                float mu  = S * (1.f / L_LEN);
                float var = fmaxf(Q * (1.f / L_LEN) - mu * mu, 0.f);
                float sd  = sqrtf(var) + 1e-6f;
                sty[w] = 1.f / (sd * (float)L_LEN);
                S += xn[e] - v[e];
                Q += xn[e] * xn[e] - v[e] * v[e];
            }
        }
    }
    __syncthreads();                         // xb + sty ready

    // ---- chunk loop: 16 MFMA(32x32x16)/wave/chunk ----
    float16v z16;
    #pragma unroll
    for (int i = 0; i < 16; ++i) z16[i] = 0.f;
    float vm0 = -1e30f, vm1 = -1e30f;

    #pragma unroll 1
    for (int ci = 0; ci < 32; ++ci) {
        const int T0 = (ci < 31) ? ci * 128 : (NWIN - 128);  // last overlaps
        const int e  = T0 + 32 * mt + m32;
        const int c  = e & 7;
        const int rb = e & ~7;
        const int base = c * XSTR + rb + 8 * h;   // elem; +16ks+j per frag

        short8 af[8];
        #pragma unroll
        for (int ks = 0; ks < 8; ++ks) {
            short4v lo = *(const short4v*)&xb[base + 16 * ks];
            short4v hi = *(const short4v*)&xb[base + 16 * ks + 4];
            af[ks] = __builtin_shufflevector(lo, hi, 0, 1, 2, 3, 4, 5, 6, 7);
        }

        float sv[16];
        const int wb = T0 + 32 * mt + 4 * h;
        #pragma unroll
        for (int Q = 0; Q < 4; ++Q)
            #pragma unroll
            for (int rr = 0; rr < 4; ++rr)
                sv[4 * Q + rr] = sty[wb + 8 * Q + rr];

        float16v acc0 = __builtin_amdgcn_mfma_f32_32x32x16_bf16(af[0], Bf[0][0], z16, 0, 0, 0);
        float16v acc1 = __builtin_amdgcn_mfma_f32_32x32x16_bf16(af[0], Bf[1][0], z16, 0, 0, 0);
        #pragma unroll
        for (int ks = 1; ks < 8; ++ks) {
            acc0 = __builtin_amdgcn_mfma_f32_32x32x16_bf16(af[ks], Bf[0][ks], acc0, 0, 0, 0);
            acc1 = __builtin_amdgcn_mfma_f32_32x32x16_bf16(af[ks], Bf[1][ks], acc1, 0, 0, 0);
        }

        #pragma unroll
        for (int r = 0; r < 16; ++r) {
            vm0 = fmaxf(vm0, acc0[r] * sv[r]);
            vm1 = fmaxf(vm1, acc1[r] * sv[r]);
        }
    }

    // ---- combine h-halves, cross-wave max, direct store ----
    vm0 = fmaxf(vm0, __shfl_xor(vm0, 32));
    vm1 = fmaxf(vm1, __shfl_xor(vm1, 32));
    if (lane < 32) { wmax[wv][0][lane] = vm0; wmax[wv][1][lane] = vm1; }
    __syncthreads();
    if (tid < CK) {
        const int dh = tid >> 6, nt2 = (tid >> 5) & 1, c32 = tid & 31;
        float m = wmax[4 * dh][nt2][c32];
        #pragma unroll
        for (int mm = 1; mm < 4; ++mm)
            m = fmaxf(m, wmax[4 * dh + mm][nt2][c32]);
        out[row * CK + tid] = m;
    }
}

extern "C" void kernel_launch(void* const* d_in, const int* in_sizes, int n_in,
                              void* d_out, int out_size, void* d_ws, size_t ws_size,
                              hipStream_t stream) {
    (void)in_sizes; (void)n_in; (void)out_size; (void)ws_size;
    const float* x  = (const float*)d_in[0];
    const float* sh = (const float*)d_in[1];
    unsigned short* wsB = (unsigned short*)d_ws;   // 32 KB (proven safe)
    float* out = (float*)d_out;

    prep_sh<<<128, 128, 0, stream>>>(sh, wsB);
    conv_row<<<256, 512, 0, stream>>>(x, wsB, out);
}

// Round 11
// 86.514 us; speedup vs baseline: 1.0296x; 1.0296x over previous
//
#include <hip/hip_runtime.h>
#include <hip/hip_bf16.h>

typedef __attribute__((ext_vector_type(8))) short short8;
typedef __attribute__((ext_vector_type(4))) float float4v;

#define T_LEN 4096
#define L_LEN 128
#define NWIN  3969
#define CK    128

__device__ __forceinline__ unsigned short f2bf(float f) {
    unsigned u = __float_as_uint(f);
    u += 0x7fffu + ((u >> 16) & 1u);          // RNE
    return (unsigned short)(u >> 16);
}

// 128 blocks x 128 threads: normalize shapelet ck=blockIdx, write B-swizzled
__global__ void prep_sh(const float* __restrict__ sh,
                        unsigned short* __restrict__ wsB) {
    const int ck = blockIdx.x;       // 0..127
    const int l  = threadIdx.x;      // 0..127
    __shared__ float rs[2], rq[2];
    const int lane = l & 63, wv = l >> 6;

    float v = sh[ck * L_LEN + l];
    float s = v, q = v * v;
    #pragma unroll
    for (int off = 32; off >= 1; off >>= 1) {
        s += __shfl_xor(s, off);
        q += __shfl_xor(q, off);
    }
    if (lane == 0) { rs[wv] = s; rq[wv] = q; }
    __syncthreads();
    float sm = rs[0] + rs[1], sq = rq[0] + rq[1];
    float mu  = sm * (1.f / L_LEN);
    float var = fmaxf(sq * (1.f / L_LEN) - mu * mu, 0.f);
    float inv = 1.f / (sqrtf(var) + 1e-6f);
    unsigned short b = f2bf((v - mu) * inv);
    // B-operand fragment order: lane' = qd*16 + n, 8 contiguous bf16
    const int nt = ck >> 4, n = ck & 15;
    const int kt = l >> 5, qd = (l >> 3) & 3, jj = l & 7;
    wsB[((((nt * 4 + kt) * 64) + qd * 16 + n) << 3) + jj] = b;
}

// one block per row; 512 threads = 8 waves; 2 waves/SIMD (256-reg budget):
// B fragments live in 128 registers for the whole row. wave w owns windows
// T0 + w + 8m (m=0..15): A-frag = one aligned ds_read_b128 from shifted
// copy (T0+w)&7. Chunk loop: no barriers, no acc-init, A-frag prefetch,
// deferred (packed) max epilogue.
__global__ __launch_bounds__(512, 2)
void conv_row(const float* __restrict__ x,
              const unsigned short* __restrict__ wsB,
              float* __restrict__ out) {
    __shared__ alignas(16) unsigned short xb[8][T_LEN]; // 64 KB shifted copies
    __shared__ float sty[T_LEN];                        // 16 KB: 1/(sd*L)
    __shared__ float PSs[513], PQs[513];                // prefix sums @8-elem
    __shared__ float grpS[8], grpQ[8];
    __shared__ float wmax[8][CK];                       // 4 KB

    const int tid  = threadIdx.x;
    const int lane = tid & 63;
    const int wv   = tid >> 6;
    const int row  = blockIdx.x;
    const float4* xr4 = (const float4*)(x + row * T_LEN);

    // ---- B fragments -> 128 registers (issued first: long latency) ----
    short8 Bf[8][4];
    {
        const short8* Bp = (const short8*)wsB;
        #pragma unroll
        for (int nt = 0; nt < 8; ++nt)
            #pragma unroll
            for (int kt = 0; kt < 4; ++kt)
                Bf[nt][kt] = Bp[(nt * 4 + kt) * 64 + lane];
    }

    // ---- stage row: thread t owns elems [8t,8t+8), loads 16 (overlap) ----
    float v[16];
    {
        float4 a0 = xr4[2 * tid];
        float4 a1 = xr4[2 * tid + 1];
        float4 a2 = make_float4(0.f, 0.f, 0.f, 0.f), a3 = a2;
        if (tid < 511) { a2 = xr4[2 * tid + 2]; a3 = xr4[2 * tid + 3]; }
        v[0]=a0.x; v[1]=a0.y; v[2]=a0.z;  v[3]=a0.w;
        v[4]=a1.x; v[5]=a1.y; v[6]=a1.z;  v[7]=a1.w;
        v[8]=a2.x; v[9]=a2.y; v[10]=a2.z; v[11]=a2.w;
        v[12]=a3.x; v[13]=a3.y; v[14]=a3.z; v[15]=a3.w;
    }
    unsigned short bb[16];
    #pragma unroll
    for (int i = 0; i < 16; ++i) bb[i] = f2bf(v[i]);
    #pragma unroll
    for (int c = 0; c < 8; ++c) {           // copy_c[i] = x[i+c]; aligned b128
        short8 w8;
        #pragma unroll
        for (int j = 0; j < 8; ++j) w8[j] = (short)bb[c + j];
        *(short8*)&xb[c][8 * tid] = w8;
    }

    // ---- seg sums (8 elems) + block scan -> elem-granular prefix @8 ----
    float s = 0.f, q = 0.f;
    #pragma unroll
    for (int i = 0; i < 8; ++i) { s += v[i]; q += v[i] * v[i]; }
    float is = s, iq = q;
    #pragma unroll
    for (int off = 1; off < 64; off <<= 1) {
        float ts = __shfl_up(is, off);
        float tq = __shfl_up(iq, off);
        if (lane >= off) { is += ts; iq += tq; }
    }
    if (lane == 63) { grpS[wv] = is; grpQ[wv] = iq; }
    __syncthreads();
    float os = 0.f, oq = 0.f;
    #pragma unroll
    for (int w = 0; w < 7; ++w) if (w < wv) { os += grpS[w]; oq += grpQ[w]; }
    PSs[tid] = os + is - s;                 // exclusive prefix at elem 8*tid
    PQs[tid] = oq + iq - q;
    if (tid == 511) { PSs[512] = os + is; PQs[512] = oq + iq; }
    __syncthreads();

    // ---- window stats: thread t -> windows [8t, 8t+8), incremental ----
    if (tid < 497) {
        float S = PSs[tid + 16] - PSs[tid];   // sum over [8t, 8t+128)
        float Q = PQs[tid + 16] - PQs[tid];
        float4 b0 = make_float4(0.f, 0.f, 0.f, 0.f), b1 = b0;
        if (tid <= 495) { b0 = xr4[2 * tid + 32]; b1 = xr4[2 * tid + 33]; }
        float xn[8] = {b0.x, b0.y, b0.z, b0.w, b1.x, b1.y, b1.z, b1.w};
        #pragma unroll
        for (int e = 0; e < 8; ++e) {
            int w = 8 * tid + e;
            if (w < NWIN) {
                float mu  = S * (1.f / L_LEN);
                float var = fmaxf(Q * (1.f / L_LEN) - mu * mu, 0.f);
                float sd  = sqrtf(var) + 1e-6f;
                sty[w] = 1.f / (sd * (float)L_LEN);
                S += xn[e] - v[e];
                Q += xn[e] * xn[e] - v[e] * v[e];
            }
        }
    }
    __syncthreads();                        // xb + sty ready

    // ---- chunk loop: prefetched A-frags, no acc-init, deferred max ----
    const int abase = (lane & 15) + (lane >> 4);
    const int q4    = (lane >> 4) * 4;
    const float4v z4 = float4v{0.f, 0.f, 0.f, 0.f};

    float4v vmax4[8];
    #pragma unroll
    for (int nt = 0; nt < 8; ++nt) vmax4[nt] = float4v{-1e30f,-1e30f,-1e30f,-1e30f};

    // prefetch chunk 0
    short8 af[4];
    {
        const int ci = (4 * wv) & 31;
        const int T0 = (ci < 31) ? ci * 128 : (NWIN - 128);
        const int e0 = T0 + wv;
        const int c  = e0 & 7, b8 = e0 >> 3;
        #pragma unroll
        for (int kt = 0; kt < 4; ++kt)
            af[kt] = *(const short8*)&xb[c][8 * (b8 + abase + 4 * kt)];
    }

    #pragma unroll 1                        // keep acc live-range single-iter
    for (int ii = 0; ii < 32; ++ii) {
        const int ci = (ii + 4 * wv) & 31;                   // wave-staggered
        const int T0 = (ci < 31) ? ci * 128 : (NWIN - 128);
        const int e0 = T0 + wv;

        // scale factors for this chunk
        float4v sr;
        #pragma unroll
        for (int r = 0; r < 4; ++r) sr[r] = sty[e0 + 8 * (q4 + r)];

        // next chunk's A-frags (issued before the MFMA burst)
        short8 an[4];
        {
            const int cn = ((ii + 1) + 4 * wv) & 31;
            const int Tn = (cn < 31) ? cn * 128 : (NWIN - 128);
            const int en = Tn + wv;
            const int c2 = en & 7, b82 = en >> 3;
            #pragma unroll
            for (int kt = 0; kt < 4; ++kt)
                an[kt] = *(const short8*)&xb[c2][8 * (b82 + abase + 4 * kt)];
        }

        // MFMA burst: kt=0 consumes C=0 (no acc-init)
        float4v acc[8];
        #pragma unroll
        for (int nt = 0; nt < 8; ++nt)
            acc[nt] = __builtin_amdgcn_mfma_f32_16x16x32_bf16(
                af[0], Bf[nt][0], z4, 0, 0, 0);
        #pragma unroll
        for (int kt = 1; kt < 4; ++kt)
            #pragma unroll
            for (int nt = 0; nt < 8; ++nt)
                acc[nt] = __builtin_amdgcn_mfma_f32_16x16x32_bf16(
                    af[kt], Bf[nt][kt], acc[nt], 0, 0, 0);

        // deferred elementwise max (packed-math friendly, depth-2)
        #pragma unroll
        for (int nt = 0; nt < 8; ++nt) {
            float4v t = acc[nt] * sr;
            #pragma unroll
            for (int r = 0; r < 4; ++r)
                vmax4[nt][r] = fmaxf(vmax4[nt][r], t[r]);
        }

        #pragma unroll
        for (int kt = 0; kt < 4; ++kt) af[kt] = an[kt];
    }

    // ---- reduce r-lanes, cross-lane + cross-wave max, direct store ----
    #pragma unroll
    for (int nt = 0; nt < 8; ++nt) {
        float vx = fmaxf(fmaxf(vmax4[nt][0], vmax4[nt][1]),
                         fmaxf(vmax4[nt][2], vmax4[nt][3]));
        vx = fmaxf(vx, __shfl_xor(vx, 16));
        vx = fmaxf(vx, __shfl_xor(vx, 32));
        if (lane < 16) wmax[wv][nt * 16 + lane] = vx;
    }
    __syncthreads();
    if (tid < CK) {
        float m = wmax[0][tid];
        #pragma unroll
        for (int w = 1; w < 8; ++w) m = fmaxf(m, wmax[w][tid]);
        out[row * CK + tid] = m;
    }
}

extern "C" void kernel_launch(void* const* d_in, const int* in_sizes, int n_in,
                              void* d_out, int out_size, void* d_ws, size_t ws_size,
                              hipStream_t stream) {
    (void)in_sizes; (void)n_in; (void)out_size; (void)ws_size;
    const float* x  = (const float*)d_in[0];
    const float* sh = (const float*)d_in[1];
    unsigned short* wsB = (unsigned short*)d_ws;   // 32 KB (proven safe)
    float* out = (float*)d_out;

    prep_sh<<<128, 128, 0, stream>>>(sh, wsB);
    conv_row<<<256, 512, 0, stream>>>(x, wsB, out);
}

// Round 12
// 83.999 us; speedup vs baseline: 1.0604x; 1.0299x over previous
//
#include <hip/hip_runtime.h>
#include <hip/hip_bf16.h>

typedef __attribute__((ext_vector_type(8))) short short8;
typedef __attribute__((ext_vector_type(4))) float float4v;

#define T_LEN 4096
#define L_LEN 128
#define NWIN  3969
#define CK    128

__device__ __forceinline__ unsigned short f2bf(float f) {
    unsigned u = __float_as_uint(f);
    u += 0x7fffu + ((u >> 16) & 1u);          // RNE
    return (unsigned short)(u >> 16);
}

// 128 blocks x 128 threads: normalize shapelet ck=blockIdx, write B-swizzled
__global__ void prep_sh(const float* __restrict__ sh,
                        unsigned short* __restrict__ wsB) {
    const int ck = blockIdx.x;       // 0..127
    const int l  = threadIdx.x;      // 0..127
    __shared__ float rs[2], rq[2];
    const int lane = l & 63, wv = l >> 6;

    float v = sh[ck * L_LEN + l];
    float s = v, q = v * v;
    #pragma unroll
    for (int off = 32; off >= 1; off >>= 1) {
        s += __shfl_xor(s, off);
        q += __shfl_xor(q, off);
    }
    if (lane == 0) { rs[wv] = s; rq[wv] = q; }
    __syncthreads();
    float sm = rs[0] + rs[1], sq = rq[0] + rq[1];
    float mu  = sm * (1.f / L_LEN);
    float var = fmaxf(sq * (1.f / L_LEN) - mu * mu, 0.f);
    float inv = 1.f / (sqrtf(var) + 1e-6f);
    unsigned short b = f2bf((v - mu) * inv);
    // B-operand fragment order: lane' = qd*16 + n, 8 contiguous bf16
    const int nt = ck >> 4, n = ck & 15;
    const int kt = l >> 5, qd = (l >> 3) & 3, jj = l & 7;
    wsB[((((nt * 4 + kt) * 64) + qd * 16 + n) << 3) + jj] = b;
}

// one block per row; 512 threads = 8 waves; 2 waves/SIMD (256-reg budget):
// B fragments live in 128 registers for the whole row. wave w owns windows
// T0 + w + 8m (m=0..15). Chunk loop is a ping-pong software pipeline:
// epilogue of chunk c runs only after the burst of chunk c+1 has issued,
// so acc reads never stall the matrix pipe.
__global__ __launch_bounds__(512, 2)
void conv_row(const float* __restrict__ x,
              const unsigned short* __restrict__ wsB,
              float* __restrict__ out) {
    __shared__ alignas(16) unsigned short xb[8][T_LEN]; // 64 KB shifted copies
    __shared__ float sty[T_LEN];                        // 16 KB: 1/(sd*L)
    __shared__ float PSs[513], PQs[513];                // prefix sums @8-elem
    __shared__ float grpS[8], grpQ[8];
    __shared__ float wmax[8][CK];                       // 4 KB

    const int tid  = threadIdx.x;
    const int lane = tid & 63;
    const int wv   = tid >> 6;
    const int row  = blockIdx.x;
    const float4* xr4 = (const float4*)(x + row * T_LEN);

    // ---- B fragments -> 128 registers (issued first: long latency) ----
    short8 Bf[8][4];
    {
        const short8* Bp = (const short8*)wsB;
        #pragma unroll
        for (int nt = 0; nt < 8; ++nt)
            #pragma unroll
            for (int kt = 0; kt < 4; ++kt)
                Bf[nt][kt] = Bp[(nt * 4 + kt) * 64 + lane];
    }

    // ---- stage row: thread t owns elems [8t,8t+8), loads 16 (overlap) ----
    float v[16];
    {
        float4 a0 = xr4[2 * tid];
        float4 a1 = xr4[2 * tid + 1];
        float4 a2 = make_float4(0.f, 0.f, 0.f, 0.f), a3 = a2;
        if (tid < 511) { a2 = xr4[2 * tid + 2]; a3 = xr4[2 * tid + 3]; }
        v[0]=a0.x; v[1]=a0.y; v[2]=a0.z;  v[3]=a0.w;
        v[4]=a1.x; v[5]=a1.y; v[6]=a1.z;  v[7]=a1.w;
        v[8]=a2.x; v[9]=a2.y; v[10]=a2.z; v[11]=a2.w;
        v[12]=a3.x; v[13]=a3.y; v[14]=a3.z; v[15]=a3.w;
    }
    unsigned short bb[16];
    #pragma unroll
    for (int i = 0; i < 16; ++i) bb[i] = f2bf(v[i]);
    #pragma unroll
    for (int c = 0; c < 8; ++c) {           // copy_c[i] = x[i+c]; aligned b128
        short8 w8;
        #pragma unroll
        for (int j = 0; j < 8; ++j) w8[j] = (short)bb[c + j];
        *(short8*)&xb[c][8 * tid] = w8;
    }

    // ---- seg sums (8 elems) + block scan -> elem-granular prefix @8 ----
    float s = 0.f, q = 0.f;
    #pragma unroll
    for (int i = 0; i < 8; ++i) { s += v[i]; q += v[i] * v[i]; }
    float is = s, iq = q;
    #pragma unroll
    for (int off = 1; off < 64; off <<= 1) {
        float ts = __shfl_up(is, off);
        float tq = __shfl_up(iq, off);
        if (lane >= off) { is += ts; iq += tq; }
    }
    if (lane == 63) { grpS[wv] = is; grpQ[wv] = iq; }
    __syncthreads();
    float os = 0.f, oq = 0.f;
    #pragma unroll
    for (int w = 0; w < 7; ++w) if (w < wv) { os += grpS[w]; oq += grpQ[w]; }
    PSs[tid] = os + is - s;                 // exclusive prefix at elem 8*tid
    PQs[tid] = oq + iq - q;
    if (tid == 511) { PSs[512] = os + is; PQs[512] = oq + iq; }
    __syncthreads();

    // ---- window stats: thread t -> windows [8t, 8t+8), incremental ----
    if (tid < 497) {
        float S = PSs[tid + 16] - PSs[tid];   // sum over [8t, 8t+128)
        float Q = PQs[tid + 16] - PQs[tid];
        float4 b0 = make_float4(0.f, 0.f, 0.f, 0.f), b1 = b0;
        if (tid <= 495) { b0 = xr4[2 * tid + 32]; b1 = xr4[2 * tid + 33]; }
        float xn[8] = {b0.x, b0.y, b0.z, b0.w, b1.x, b1.y, b1.z, b1.w};
        #pragma unroll
        for (int e = 0; e < 8; ++e) {
            int w = 8 * tid + e;
            if (w < NWIN) {
                float mu  = S * (1.f / L_LEN);
                float var = fmaxf(Q * (1.f / L_LEN) - mu * mu, 0.f);
                float sd  = sqrtf(var) + 1e-6f;
                sty[w] = 1.f / (sd * (float)L_LEN);
                S += xn[e] - v[e];
                Q += xn[e] * xn[e] - v[e] * v[e];
            }
        }
    }
    __syncthreads();                        // xb + sty ready

    // ---- ping-pong pipelined chunk loop ----
    const int abase = (lane & 15) + (lane >> 4);
    const int q4    = (lane >> 4) * 4;
    const float4v z4 = float4v{0.f, 0.f, 0.f, 0.f};

    float vmax[8];
    #pragma unroll
    for (int nt = 0; nt < 8; ++nt) vmax[nt] = -1e30f;

    short8  afA[4], afB[4];
    float4v accA[8], accB[8];
    float4v srA, srB;

    // chunk index with per-wave offset (even, so pairs stay pairs)
    auto T0of = [&](int c) {
        int ci = (c + 4 * wv) & 31;
        return (ci < 31) ? ci * 128 : (NWIN - 128);
    };
    auto loadA = [&](int c, short8 af[4]) {
        const int e0 = T0of(c) + wv;
        const int cc = e0 & 7, b8 = e0 >> 3;
        #pragma unroll
        for (int kt = 0; kt < 4; ++kt)
            af[kt] = *(const short8*)&xb[cc][8 * (b8 + abase + 4 * kt)];
    };
    auto loadS = [&](int c, float4v& sr) {
        const int e0 = T0of(c) + wv;
        #pragma unroll
        for (int r = 0; r < 4; ++r) sr[r] = sty[e0 + 8 * (q4 + r)];
    };
    auto burst = [&](const short8 af[4], float4v acc[8]) {
        #pragma unroll
        for (int nt = 0; nt < 8; ++nt)
            acc[nt] = __builtin_amdgcn_mfma_f32_16x16x32_bf16(
                af[0], Bf[nt][0], z4, 0, 0, 0);
        #pragma unroll
        for (int kt = 1; kt < 4; ++kt)
            #pragma unroll
            for (int nt = 0; nt < 8; ++nt)
                acc[nt] = __builtin_amdgcn_mfma_f32_16x16x32_bf16(
                    af[kt], Bf[nt][kt], acc[nt], 0, 0, 0);
    };
    auto epi = [&](const float4v acc[8], const float4v& sr) {
        #pragma unroll
        for (int nt = 0; nt < 8; ++nt) {
            float4v t = acc[nt] * sr;
            vmax[nt] = fmaxf(vmax[nt],
                             fmaxf(fmaxf(t[0], t[1]), fmaxf(t[2], t[3])));
        }
    };

    // prologue: chunks 0,1; establish invariant for p=1
    loadA(0, afA); loadS(0, srA);
    burst(afA, accA);                      // B(0)
    loadA(1, afB); loadS(1, srB);
    burst(afB, accB);                      // B(1)
    loadA(2, afA);
    epi(accA, srA);                        // E(0)

    #pragma unroll 1
    for (int p = 1; p <= 15; ++p) {
        // invariant: afA = frags(2p), accB = B(2p-1), srB = sr(2p-1)
        loadS(2 * p, srA);
        burst(afA, accA);                  // B(2p)
        loadA(2 * p + 1, afB);
        epi(accB, srB);                    // E(2p-1): acc is a full burst old
        loadS(2 * p + 1, srB);
        burst(afB, accB);                  // B(2p+1)
        loadA(2 * p + 2, afA);             // p=15 wraps to chunk 0: harmless
        epi(accA, srA);                    // E(2p)
    }
    epi(accB, srB);                        // E(31)

    // ---- cross-lane + cross-wave max, direct store ----
    #pragma unroll
    for (int nt = 0; nt < 8; ++nt) {
        float vx = vmax[nt];
        vx = fmaxf(vx, __shfl_xor(vx, 16));
        vx = fmaxf(vx, __shfl_xor(vx, 32));
        if (lane < 16) wmax[wv][nt * 16 + lane] = vx;
    }
    __syncthreads();
    if (tid < CK) {
        float m = wmax[0][tid];
        #pragma unroll
        for (int w = 1; w < 8; ++w) m = fmaxf(m, wmax[w][tid]);
        out[row * CK + tid] = m;
    }
}

extern "C" void kernel_launch(void* const* d_in, const int* in_sizes, int n_in,
                              void* d_out, int out_size, void* d_ws, size_t ws_size,
                              hipStream_t stream) {
    (void)in_sizes; (void)n_in; (void)out_size; (void)ws_size;
    const float* x  = (const float*)d_in[0];
    const float* sh = (const float*)d_in[1];
    unsigned short* wsB = (unsigned short*)d_ws;   // 32 KB (proven safe)
    float* out = (float*)d_out;

    prep_sh<<<128, 128, 0, stream>>>(sh, wsB);
    conv_row<<<256, 512, 0, stream>>>(x, wsB, out);
}